// Round 7
// baseline (142.088 us; speedup 1.0000x reference)
//
#include <hip/hip_runtime.h>
#include <hip/hip_bf16.h>

typedef __bf16 bf16x8 __attribute__((ext_vector_type(8)));
typedef __bf16 bf16x4 __attribute__((ext_vector_type(4)));
typedef float  f32x4  __attribute__((ext_vector_type(4)));
typedef short  s16x4  __attribute__((ext_vector_type(4)));

#define N_NODES 100000
#define N_EDGES 1000000
#define LATENT  64
#define HID     256
#define RBF_DIM 32
#define NTYPES  10
#define NCHG    6
#define NBOND   5

#define ATOM_TILES (N_NODES / 32)   // 3125
#define ANBLK 512

#define ETILE  32
#define ETILES (N_EDGES / ETILE)    // 31250
#define ENBLK  1024                 // 4 blocks/CU

// 16x16x16 bf16 MFMA: A-frag lane holds A[m=lane&15][k=(lane>>4)*4+j] (j=0..3),
// B-frag lane holds B[k=(lane>>4)*4+j][n=lane&15]  -> matches L1's D layout.
static __device__ __forceinline__ f32x4 mfma16(bf16x4 a, bf16x4 b, f32x4 c) {
#if __has_builtin(__builtin_amdgcn_mfma_f32_16x16x16bf16_1k)
    s16x4 ai = __builtin_bit_cast(s16x4, a);
    s16x4 bi = __builtin_bit_cast(s16x4, b);
    return __builtin_amdgcn_mfma_f32_16x16x16bf16_1k(ai, bi, c, 0, 0, 0);
#else
    asm volatile("s_nop 1\n\t"
                 "v_mfma_f32_16x16x16_bf16 %0, %1, %2, %0\n\t"
                 "s_nop 7\n\ts_nop 7"
                 : "+v"(c) : "v"(a), "v"(b));
    return c;
#endif
}

// ---------------------------------------------------------------------------
// Atom MLP via MFMA; also emits qb = bf16(q). (proven, ~2.5 us)
// ---------------------------------------------------------------------------
struct __align__(16) ASmem {
    __bf16 qs[32][72];
    __bf16 hsE[32][264];
    float  red[4][2][4][64];
};

template<bool EMIT_QB>
__global__ __launch_bounds__(256, 2) void atom_kernel(
    const float* __restrict__ q,   const float* __restrict__ aW1,
    const float* __restrict__ ab1, const float* __restrict__ aW2,
    const float* __restrict__ ab2, float* __restrict__ outA,
    float* __restrict__ outB,      __bf16* __restrict__ qb)
{
    __shared__ ASmem sm;
    const int t    = threadIdx.x;
    const int w    = t >> 6;
    const int lane = t & 63;
    const int l15  = lane & 15;
    const int hi   = lane >> 4;
    const int wcol = w * 64;

    bf16x8 aw1f[2][4];
    #pragma unroll
    for (int kb = 0; kb < 2; ++kb)
        #pragma unroll
        for (int nt = 0; nt < 4; ++nt) {
            const int nn = wcol + nt * 16 + l15;
            const int k0 = kb * 32 + hi * 8;
            bf16x8 v;
            #pragma unroll
            for (int j = 0; j < 8; ++j) v[j] = (__bf16)aW1[(k0 + j) * HID + nn];
            aw1f[kb][nt] = v;
        }
    bf16x8 aw2f[2];
    #pragma unroll
    for (int kk = 0; kk < 2; ++kk) {
        const int k0 = (w * 2 + kk) * 32 + hi * 8;
        bf16x8 v;
        #pragma unroll
        for (int j = 0; j < 8; ++j) v[j] = (__bf16)aW2[(k0 + j) * 16 + l15];
        aw2f[kk] = v;
    }
    float4 b1v[4];
    #pragma unroll
    for (int nt = 0; nt < 4; ++nt)
        b1v[nt] = *(const float4*)(&ab1[wcol + nt * 16 + hi * 4]);

    const int m_st = t >> 3;
    const int p_st = t & 7;

    for (int tile = blockIdx.x; tile < ATOM_TILES; tile += ANBLK) {
        const int node0 = tile * 32;
        {
            const float* qr = q + (size_t)(node0 + m_st) * 64 + p_st * 8;
            const float4 a0 = *(const float4*)(qr);
            const float4 a1 = *(const float4*)(qr + 4);
            bf16x8 v;
            v[0] = (__bf16)a0.x; v[1] = (__bf16)a0.y; v[2] = (__bf16)a0.z; v[3] = (__bf16)a0.w;
            v[4] = (__bf16)a1.x; v[5] = (__bf16)a1.y; v[6] = (__bf16)a1.z; v[7] = (__bf16)a1.w;
            *(bf16x8*)(&sm.qs[m_st][p_st * 8]) = v;
            if constexpr (EMIT_QB)
                *(bf16x8*)(qb + (size_t)(node0 + m_st) * 64 + p_st * 8) = v;
        }
        __syncthreads();

        f32x4 acc[2][4];
        #pragma unroll
        for (int mt = 0; mt < 2; ++mt)
            #pragma unroll
            for (int nt = 0; nt < 4; ++nt)
                #pragma unroll
                for (int r = 0; r < 4; ++r)
                    acc[mt][nt][r] = ((const float*)&b1v[nt])[r];

        #pragma unroll
        for (int kb = 0; kb < 2; ++kb)
            #pragma unroll
            for (int mt = 0; mt < 2; ++mt) {
                const bf16x8 bq = *(const bf16x8*)((const char*)&sm.qs[0][0]
                                   + (mt * 16 + l15) * 144 + kb * 64 + hi * 16);
                #pragma unroll
                for (int nt = 0; nt < 4; ++nt)
                    acc[mt][nt] = __builtin_amdgcn_mfma_f32_16x16x32_bf16(
                        aw1f[kb][nt], bq, acc[mt][nt], 0, 0, 0);
            }

        #pragma unroll
        for (int mt = 0; mt < 2; ++mt)
            #pragma unroll
            for (int nt = 0; nt < 4; ++nt) {
                bf16x4 hv;
                #pragma unroll
                for (int r = 0; r < 4; ++r)
                    hv[r] = (__bf16)fmaxf(acc[mt][nt][r], 0.f);
                *(bf16x4*)(&sm.hsE[mt * 16 + l15][wcol + nt * 16 + hi * 4]) = hv;
            }
        __syncthreads();

        f32x4 acc2[2];
        {
            f32x4 z = {0.f, 0.f, 0.f, 0.f};
            acc2[0] = z; acc2[1] = z;
        }
        #pragma unroll
        for (int mt = 0; mt < 2; ++mt)
            #pragma unroll
            for (int kk = 0; kk < 2; ++kk) {
                const int kb = w * 2 + kk;
                const bf16x8 af = *(const bf16x8*)((const char*)&sm.hsE[0][0]
                                   + (mt * 16 + l15) * 528 + kb * 64 + hi * 16);
                acc2[mt] = __builtin_amdgcn_mfma_f32_16x16x32_bf16(
                    af, aw2f[kk], acc2[mt], 0, 0, 0);
            }
        #pragma unroll
        for (int mt = 0; mt < 2; ++mt)
            #pragma unroll
            for (int r = 0; r < 4; ++r)
                sm.red[w][mt][r][lane] = acc2[mt][r];
        __syncthreads();

        {
            const int o  = t & 15;
            const int m0 = t >> 4;
            #pragma unroll
            for (int half = 0; half < 2; ++half) {
                const int m  = m0 + half * 16;
                const int mt = m >> 4, rr = m & 15;
                const int hh = rr >> 2, r = rr & 3;
                float s = ab2[o];
                #pragma unroll
                for (int ww = 0; ww < 4; ++ww) s += sm.red[ww][mt][r][hh * 16 + o];
                const int node = node0 + m;
                if (o < NTYPES) outA[node * NTYPES + o] = s;
                else            outB[node * NCHG + (o - NTYPES)] = s;
            }
        }
        __syncthreads();
    }
}

// ---------------------------------------------------------------------------
// Edge MLP v7: hsE ELIMINATED. Layer-2 computed in-register from layer-1
// accumulators via v_mfma_f32_16x16x16_bf16 (A-frag layout == L1 D layout).
// 256 threads (4 waves), 32-edge tiles, 64 hidden/wave, 1 barrier/tile,
// comb+red double-buffered, epilogue pipelined 1 tile back.
// LDS 29.7 KB -> 4 blocks/CU.
// ---------------------------------------------------------------------------
struct __align__(16) ESmem {
    __bf16 comb[2][ETILE][104];   // 13312 B (208 B rows)
    float  red[2][4][2][4][64];   // 16384 B
};                                // 29696 B

__device__ __forceinline__ void bar_lgkm() {
    asm volatile("s_waitcnt lgkmcnt(0)" ::: "memory");
    __builtin_amdgcn_s_barrier();
}

template<bool USEBF>
__global__ __launch_bounds__(256, 4) void edge_kernel(
    const float* __restrict__ pos, const float* __restrict__ qf,
    const __bf16* __restrict__ qb, const int* __restrict__ pair,
    const float* __restrict__ bW1, const float* __restrict__ bb1,
    const float* __restrict__ bW2, const float* __restrict__ bb2,
    float* __restrict__ outC)
{
    __shared__ ESmem sm;
    const int t    = threadIdx.x;
    const int w    = t >> 6;           // 0..3
    const int lane = t & 63;
    const int l15  = lane & 15;
    const int hi   = lane >> 4;
    const int hid0 = w * 64;           // wave's hidden slice

    // W1^T fragments: this wave's 64 hidden cols (48 VGPR)
    bf16x8 bw1f[3][4];
    #pragma unroll
    for (int kb = 0; kb < 3; ++kb)
        #pragma unroll
        for (int nt = 0; nt < 4; ++nt) {
            const int nn = hid0 + nt * 16 + l15;
            const int k0 = kb * 32 + hi * 8;
            bf16x8 v;
            #pragma unroll
            for (int j = 0; j < 8; ++j) v[j] = (__bf16)bW1[(k0 + j) * HID + nn];
            bw1f[kb][nt] = v;
        }
    // W2 B-frags for 16x16x16: B[k=hi*4+j][n=l15] over this wave's K-slice.
    // w2f[nt][j] = W2[hid0 + nt*16 + hi*4 + j][l15]  (8 VGPR)
    bf16x4 w2f[4];
    #pragma unroll
    for (int nt = 0; nt < 4; ++nt) {
        bf16x4 v;
        #pragma unroll
        for (int j = 0; j < 4; ++j)
            v[j] = (l15 < NBOND)
                 ? (__bf16)bW2[(hid0 + nt * 16 + hi * 4 + j) * NBOND + l15]
                 : (__bf16)0.f;
        w2f[nt] = v;
    }
    float4 b1v[4];
    #pragma unroll
    for (int nt = 0; nt < 4; ++nt)
        b1v[nt] = *(const float4*)(&bb1[hid0 + nt * 16 + hi * 4]);

    const int e_loc = t >> 3;   // 0..31
    const int p     = t & 7;

    int tile = blockIdx.x;
    bf16x8 gs, gd;
    float4 fs0, fs1, fd0, fd1;
    float  ps0, ps1, ps2, pd0, pd1, pd2;
    int2 pA = ((const int2*)pair)[(size_t)tile * ETILE + e_loc];
    #define GATHER(pN)                                                            \
        if constexpr (USEBF) {                                                    \
            gs = *(const bf16x8*)(qb + ((unsigned)(pN).x * 64u + (unsigned)(p*8)));\
            gd = *(const bf16x8*)(qb + ((unsigned)(pN).y * 64u + (unsigned)(p*8)));\
        } else {                                                                  \
            fs0 = *(const float4*)(qf + ((unsigned)(pN).x * 64u + (unsigned)(p*8)));     \
            fs1 = *(const float4*)(qf + ((unsigned)(pN).x * 64u + (unsigned)(p*8) + 4u));\
            fd0 = *(const float4*)(qf + ((unsigned)(pN).y * 64u + (unsigned)(p*8)));     \
            fd1 = *(const float4*)(qf + ((unsigned)(pN).y * 64u + (unsigned)(p*8) + 4u));\
        }                                                                         \
        ps0 = pos[(unsigned)(pN).x * 3u];  ps1 = pos[(unsigned)(pN).x * 3u + 1u]; \
        ps2 = pos[(unsigned)(pN).x * 3u + 2u];                                    \
        pd0 = pos[(unsigned)(pN).y * 3u];  pd1 = pos[(unsigned)(pN).y * 3u + 1u]; \
        pd2 = pos[(unsigned)(pN).y * 3u + 2u];

    #define STAGE(buf)                                                            \
        {                                                                         \
            bf16x8 cv;                                                            \
            if constexpr (USEBF) {                                                \
                _Pragma("unroll")                                                 \
                for (int j = 0; j < 8; ++j)                                       \
                    cv[j] = (__bf16)((float)gs[j] + (float)gd[j]);                \
            } else {                                                              \
                cv[0] = (__bf16)(fs0.x + fd0.x); cv[1] = (__bf16)(fs0.y + fd0.y); \
                cv[2] = (__bf16)(fs0.z + fd0.z); cv[3] = (__bf16)(fs0.w + fd0.w); \
                cv[4] = (__bf16)(fs1.x + fd1.x); cv[5] = (__bf16)(fs1.y + fd1.y); \
                cv[6] = (__bf16)(fs1.z + fd1.z); cv[7] = (__bf16)(fs1.w + fd1.w); \
            }                                                                     \
            *(bf16x8*)(&sm.comb[buf][e_loc][p * 8]) = cv;                         \
            const float dx = ps0 - pd0, dy = ps1 - pd1, dz = ps2 - pd2;           \
            const float D  = sqrtf(fmaxf(dx * dx + dy * dy + dz * dz, 1e-8f));    \
            bf16x4 rv;                                                            \
            _Pragma("unroll")                                                     \
            for (int j = 0; j < 4; ++j) {                                         \
                const float mu = (float)(p * 4 + j) * (10.0f / 31.0f);            \
                const float z  = (D - mu) * 3.2f;                                 \
                rv[j] = (__bf16)__expf(-z * z);                                   \
            }                                                                     \
            *(bf16x4*)(&sm.comb[buf][e_loc][64 + p * 4]) = rv;                    \
        }

    GATHER(pA);
    {
        const int tn = tile + ENBLK;
        pA = ((const int2*)pair)[(tn < ETILES ? (size_t)tn * ETILE : 0) + e_loc];
    }
    STAGE(0);
    GATHER(pA);
    {
        const int tn = tile + 2 * ENBLK;
        pA = ((const int2*)pair)[(tn < ETILES ? (size_t)tn * ETILE : 0) + e_loc];
    }
    bar_lgkm();

    int cur = 0;
    int e0_prev = -1;

    for (; tile < ETILES; tile += ENBLK) {
        const int e0 = tile * ETILE;

        // 1. epilogue for previous tile
        if (e0_prev >= 0 && t < 160) {
            const int m = t / 5, o = t % 5;
            const int mt = m >> 4, rr = m & 15;
            const int hh = rr >> 2, r = rr & 3;
            float s = bb2[o];
            #pragma unroll
            for (int ww = 0; ww < 4; ++ww)
                s += sm.red[cur ^ 1][ww][mt][r][hh * 16 + o];
            outC[(size_t)(e0_prev + m) * NBOND + o] = s;
        }

        // 2. stage comb[cur^1] from in-flight gathers
        STAGE(cur ^ 1);

        // 3. issue gathers for tile+2*ENBLK; pair for tile+3*ENBLK
        GATHER(pA);
        {
            const int tn = tile + 3 * ENBLK;
            pA = ((const int2*)pair)[(tn < ETILES ? (size_t)tn * ETILE : 0) + e_loc];
        }

        // 4. layer 1 on comb[cur]: wave = 64 hidden x 32 edges
        f32x4 acc[2][4];
        #pragma unroll
        for (int mt = 0; mt < 2; ++mt)
            #pragma unroll
            for (int nt = 0; nt < 4; ++nt)
                #pragma unroll
                for (int r = 0; r < 4; ++r)
                    acc[mt][nt][r] = ((const float*)&b1v[nt])[r];

        #pragma unroll
        for (int kb = 0; kb < 3; ++kb)
            #pragma unroll
            for (int mt = 0; mt < 2; ++mt) {
                const bf16x8 bf = *(const bf16x8*)((const char*)&sm.comb[cur][0][0]
                                   + (mt * 16 + l15) * 208 + kb * 64 + hi * 16);
                #pragma unroll
                for (int nt = 0; nt < 4; ++nt)
                    acc[mt][nt] = __builtin_amdgcn_mfma_f32_16x16x32_bf16(
                        bw1f[kb][nt], bf, acc[mt][nt], 0, 0, 0);
            }

        // 5. layer 2 fully in-register: relu+pack -> 16x16x16 MFMA chain
        {
            f32x4 acc2[2];
            {
                f32x4 z = {0.f, 0.f, 0.f, 0.f};
                acc2[0] = z; acc2[1] = z;
            }
            #pragma unroll
            for (int mt = 0; mt < 2; ++mt)
                #pragma unroll
                for (int nt = 0; nt < 4; ++nt) {
                    bf16x4 hv;
                    #pragma unroll
                    for (int r = 0; r < 4; ++r)
                        hv[r] = (__bf16)fmaxf(acc[mt][nt][r], 0.f);
                    acc2[mt] = mfma16(hv, w2f[nt], acc2[mt]);
                }
            #pragma unroll
            for (int mt = 0; mt < 2; ++mt)
                #pragma unroll
                for (int r = 0; r < 4; ++r)
                    sm.red[cur][w][mt][r][lane] = acc2[mt][r];
        }

        e0_prev = e0;
        bar_lgkm();     // comb[cur^1] + red[cur] visible
        cur ^= 1;
    }

    // final epilogue
    if (e0_prev >= 0 && t < 160) {
        const int m = t / 5, o = t % 5;
        const int mt = m >> 4, rr = m & 15;
        const int hh = rr >> 2, r = rr & 3;
        float s = bb2[o];
        #pragma unroll
        for (int ww = 0; ww < 4; ++ww)
            s += sm.red[cur ^ 1][ww][mt][r][hh * 16 + o];
        outC[(size_t)(e0_prev + m) * NBOND + o] = s;
    }
    #undef GATHER
    #undef STAGE
}

// ---------------------------------------------------------------------------
extern "C" void kernel_launch(void* const* d_in, const int* in_sizes, int n_in,
                              void* d_out, int out_size, void* d_ws, size_t ws_size,
                              hipStream_t stream)
{
    const float* pos = (const float*)d_in[0];
    const float* q   = (const float*)d_in[1];
    const int*   pair= (const int*)  d_in[2];
    const float* aW1 = (const float*)d_in[3];
    const float* ab1 = (const float*)d_in[4];
    const float* aW2 = (const float*)d_in[5];
    const float* ab2 = (const float*)d_in[6];
    const float* bW1 = (const float*)d_in[7];
    const float* bb1 = (const float*)d_in[8];
    const float* bW2 = (const float*)d_in[9];
    const float* bb2 = (const float*)d_in[10];

    float* out  = (float*)d_out;
    float* outA = out;
    float* outB = out + (size_t)N_NODES * NTYPES;
    float* outC = out + (size_t)N_NODES * (NTYPES + NCHG);

    const size_t qb_bytes = (size_t)N_NODES * LATENT * sizeof(__bf16);
    const bool use_bf = (ws_size >= qb_bytes);
    __bf16* qb = (__bf16*)d_ws;

    if (use_bf)
        hipLaunchKernelGGL(atom_kernel<true>, dim3(ANBLK), dim3(256), 0, stream,
                           q, aW1, ab1, aW2, ab2, outA, outB, qb);
    else
        hipLaunchKernelGGL(atom_kernel<false>, dim3(ANBLK), dim3(256), 0, stream,
                           q, aW1, ab1, aW2, ab2, outA, outB, qb);

    if (use_bf)
        hipLaunchKernelGGL(edge_kernel<true>, dim3(ENBLK), dim3(256), 0, stream,
                           pos, q, qb, pair, bW1, bb1, bW2, bb2, outC);
    else
        hipLaunchKernelGGL(edge_kernel<false>, dim3(ENBLK), dim3(256), 0, stream,
                           pos, q, qb, pair, bW1, bb1, bW2, bb2, outC);
}

// Round 8
// 100.699 us; speedup vs baseline: 1.4110x; 1.4110x over previous
//
#include <hip/hip_runtime.h>
#include <hip/hip_bf16.h>

typedef __bf16 bf16x8 __attribute__((ext_vector_type(8)));
typedef __bf16 bf16x4 __attribute__((ext_vector_type(4)));
typedef float  f32x4  __attribute__((ext_vector_type(4)));
typedef short  s16x4  __attribute__((ext_vector_type(4)));

#define N_NODES 100000
#define N_EDGES 1000000
#define LATENT  64
#define HID     256
#define RBF_DIM 32
#define NTYPES  10
#define NCHG    6
#define NBOND   5

#define ATOM_TILES (N_NODES / 32)   // 3125
#define ANBLK 512

#define ETILE  32
#define ETILES (N_EDGES / ETILE)    // 31250
#define ENBLK  768                  // 3 blocks/CU x 256 CUs (matches residency)

// 16x16x16 bf16 MFMA: A-frag lane holds A[m=lane&15][k=(lane>>4)*4+j] (j=0..3),
// B-frag lane holds B[k=(lane>>4)*4+j][n=lane&15]  -> matches L1's D layout.
// Verified numerically in round 7 (absmax 0.0078, identical to 32-K path).
static __device__ __forceinline__ f32x4 mfma16(bf16x4 a, bf16x4 b, f32x4 c) {
#if __has_builtin(__builtin_amdgcn_mfma_f32_16x16x16bf16_1k)
    s16x4 ai = __builtin_bit_cast(s16x4, a);
    s16x4 bi = __builtin_bit_cast(s16x4, b);
    return __builtin_amdgcn_mfma_f32_16x16x16bf16_1k(ai, bi, c, 0, 0, 0);
#else
    asm volatile("s_nop 1\n\t"
                 "v_mfma_f32_16x16x16_bf16 %0, %1, %2, %0\n\t"
                 "s_nop 7\n\ts_nop 7"
                 : "+v"(c) : "v"(a), "v"(b));
    return c;
#endif
}

// ---------------------------------------------------------------------------
// Atom MLP via MFMA; also emits qb = bf16(q). (proven, ~2.5 us)
// ---------------------------------------------------------------------------
struct __align__(16) ASmem {
    __bf16 qs[32][72];
    __bf16 hsE[32][264];
    float  red[4][2][4][64];
};

template<bool EMIT_QB>
__global__ __launch_bounds__(256, 2) void atom_kernel(
    const float* __restrict__ q,   const float* __restrict__ aW1,
    const float* __restrict__ ab1, const float* __restrict__ aW2,
    const float* __restrict__ ab2, float* __restrict__ outA,
    float* __restrict__ outB,      __bf16* __restrict__ qb)
{
    __shared__ ASmem sm;
    const int t    = threadIdx.x;
    const int w    = t >> 6;
    const int lane = t & 63;
    const int l15  = lane & 15;
    const int hi   = lane >> 4;
    const int wcol = w * 64;

    bf16x8 aw1f[2][4];
    #pragma unroll
    for (int kb = 0; kb < 2; ++kb)
        #pragma unroll
        for (int nt = 0; nt < 4; ++nt) {
            const int nn = wcol + nt * 16 + l15;
            const int k0 = kb * 32 + hi * 8;
            bf16x8 v;
            #pragma unroll
            for (int j = 0; j < 8; ++j) v[j] = (__bf16)aW1[(k0 + j) * HID + nn];
            aw1f[kb][nt] = v;
        }
    bf16x8 aw2f[2];
    #pragma unroll
    for (int kk = 0; kk < 2; ++kk) {
        const int k0 = (w * 2 + kk) * 32 + hi * 8;
        bf16x8 v;
        #pragma unroll
        for (int j = 0; j < 8; ++j) v[j] = (__bf16)aW2[(k0 + j) * 16 + l15];
        aw2f[kk] = v;
    }
    float4 b1v[4];
    #pragma unroll
    for (int nt = 0; nt < 4; ++nt)
        b1v[nt] = *(const float4*)(&ab1[wcol + nt * 16 + hi * 4]);

    const int m_st = t >> 3;
    const int p_st = t & 7;

    for (int tile = blockIdx.x; tile < ATOM_TILES; tile += ANBLK) {
        const int node0 = tile * 32;
        {
            const float* qr = q + (size_t)(node0 + m_st) * 64 + p_st * 8;
            const float4 a0 = *(const float4*)(qr);
            const float4 a1 = *(const float4*)(qr + 4);
            bf16x8 v;
            v[0] = (__bf16)a0.x; v[1] = (__bf16)a0.y; v[2] = (__bf16)a0.z; v[3] = (__bf16)a0.w;
            v[4] = (__bf16)a1.x; v[5] = (__bf16)a1.y; v[6] = (__bf16)a1.z; v[7] = (__bf16)a1.w;
            *(bf16x8*)(&sm.qs[m_st][p_st * 8]) = v;
            if constexpr (EMIT_QB)
                *(bf16x8*)(qb + (size_t)(node0 + m_st) * 64 + p_st * 8) = v;
        }
        __syncthreads();

        f32x4 acc[2][4];
        #pragma unroll
        for (int mt = 0; mt < 2; ++mt)
            #pragma unroll
            for (int nt = 0; nt < 4; ++nt)
                #pragma unroll
                for (int r = 0; r < 4; ++r)
                    acc[mt][nt][r] = ((const float*)&b1v[nt])[r];

        #pragma unroll
        for (int kb = 0; kb < 2; ++kb)
            #pragma unroll
            for (int mt = 0; mt < 2; ++mt) {
                const bf16x8 bq = *(const bf16x8*)((const char*)&sm.qs[0][0]
                                   + (mt * 16 + l15) * 144 + kb * 64 + hi * 16);
                #pragma unroll
                for (int nt = 0; nt < 4; ++nt)
                    acc[mt][nt] = __builtin_amdgcn_mfma_f32_16x16x32_bf16(
                        aw1f[kb][nt], bq, acc[mt][nt], 0, 0, 0);
            }

        #pragma unroll
        for (int mt = 0; mt < 2; ++mt)
            #pragma unroll
            for (int nt = 0; nt < 4; ++nt) {
                bf16x4 hv;
                #pragma unroll
                for (int r = 0; r < 4; ++r)
                    hv[r] = (__bf16)fmaxf(acc[mt][nt][r], 0.f);
                *(bf16x4*)(&sm.hsE[mt * 16 + l15][wcol + nt * 16 + hi * 4]) = hv;
            }
        __syncthreads();

        f32x4 acc2[2];
        {
            f32x4 z = {0.f, 0.f, 0.f, 0.f};
            acc2[0] = z; acc2[1] = z;
        }
        #pragma unroll
        for (int mt = 0; mt < 2; ++mt)
            #pragma unroll
            for (int kk = 0; kk < 2; ++kk) {
                const int kb = w * 2 + kk;
                const bf16x8 af = *(const bf16x8*)((const char*)&sm.hsE[0][0]
                                   + (mt * 16 + l15) * 528 + kb * 64 + hi * 16);
                acc2[mt] = __builtin_amdgcn_mfma_f32_16x16x32_bf16(
                    af, aw2f[kk], acc2[mt], 0, 0, 0);
            }
        #pragma unroll
        for (int mt = 0; mt < 2; ++mt)
            #pragma unroll
            for (int r = 0; r < 4; ++r)
                sm.red[w][mt][r][lane] = acc2[mt][r];
        __syncthreads();

        {
            const int o  = t & 15;
            const int m0 = t >> 4;
            #pragma unroll
            for (int half = 0; half < 2; ++half) {
                const int m  = m0 + half * 16;
                const int mt = m >> 4, rr = m & 15;
                const int hh = rr >> 2, r = rr & 3;
                float s = ab2[o];
                #pragma unroll
                for (int ww = 0; ww < 4; ++ww) s += sm.red[ww][mt][r][hh * 16 + o];
                const int node = node0 + m;
                if (o < NTYPES) outA[node * NTYPES + o] = s;
                else            outB[node * NCHG + (o - NTYPES)] = s;
            }
        }
        __syncthreads();
    }
}

// ---------------------------------------------------------------------------
// Edge MLP v8 = v7 structure (hsE eliminated, in-register layer-2 via
// 16x16x16 MFMA, 1 barrier/tile, comb+red double-buffered, epilogue
// pipelined 1 tile back) with the REGISTER CAP FIXED:
// __launch_bounds__(256,3) -> ~170-reg cap (v6 proved spill-free here);
// ENBLK=768 matches 3 blocks/CU residency.
// ---------------------------------------------------------------------------
struct __align__(16) ESmem {
    __bf16 comb[2][ETILE][104];   // 13312 B (208 B rows)
    float  red[2][4][2][4][64];   // 16384 B
};                                // 29696 B

__device__ __forceinline__ void bar_lgkm() {
    asm volatile("s_waitcnt lgkmcnt(0)" ::: "memory");
    __builtin_amdgcn_s_barrier();
}

template<bool USEBF>
__global__ __launch_bounds__(256, 3) void edge_kernel(
    const float* __restrict__ pos, const float* __restrict__ qf,
    const __bf16* __restrict__ qb, const int* __restrict__ pair,
    const float* __restrict__ bW1, const float* __restrict__ bb1,
    const float* __restrict__ bW2, const float* __restrict__ bb2,
    float* __restrict__ outC)
{
    __shared__ ESmem sm;
    const int t    = threadIdx.x;
    const int w    = t >> 6;           // 0..3
    const int lane = t & 63;
    const int l15  = lane & 15;
    const int hi   = lane >> 4;
    const int hid0 = w * 64;           // wave's hidden slice

    // W1^T fragments: this wave's 64 hidden cols (48 VGPR)
    bf16x8 bw1f[3][4];
    #pragma unroll
    for (int kb = 0; kb < 3; ++kb)
        #pragma unroll
        for (int nt = 0; nt < 4; ++nt) {
            const int nn = hid0 + nt * 16 + l15;
            const int k0 = kb * 32 + hi * 8;
            bf16x8 v;
            #pragma unroll
            for (int j = 0; j < 8; ++j) v[j] = (__bf16)bW1[(k0 + j) * HID + nn];
            bw1f[kb][nt] = v;
        }
    // W2 B-frags for 16x16x16: w2f[nt][j] = W2[hid0+nt*16+hi*4+j][l15] (8 VGPR)
    bf16x4 w2f[4];
    #pragma unroll
    for (int nt = 0; nt < 4; ++nt) {
        bf16x4 v;
        #pragma unroll
        for (int j = 0; j < 4; ++j)
            v[j] = (l15 < NBOND)
                 ? (__bf16)bW2[(hid0 + nt * 16 + hi * 4 + j) * NBOND + l15]
                 : (__bf16)0.f;
        w2f[nt] = v;
    }
    float4 b1v[4];
    #pragma unroll
    for (int nt = 0; nt < 4; ++nt)
        b1v[nt] = *(const float4*)(&bb1[hid0 + nt * 16 + hi * 4]);

    const int e_loc = t >> 3;   // 0..31
    const int p     = t & 7;

    int tile = blockIdx.x;
    bf16x8 gs, gd;
    float4 fs0, fs1, fd0, fd1;
    float  ps0, ps1, ps2, pd0, pd1, pd2;
    int2 pA = ((const int2*)pair)[(size_t)tile * ETILE + e_loc];
    #define GATHER(pN)                                                            \
        if constexpr (USEBF) {                                                    \
            gs = *(const bf16x8*)(qb + ((unsigned)(pN).x * 64u + (unsigned)(p*8)));\
            gd = *(const bf16x8*)(qb + ((unsigned)(pN).y * 64u + (unsigned)(p*8)));\
        } else {                                                                  \
            fs0 = *(const float4*)(qf + ((unsigned)(pN).x * 64u + (unsigned)(p*8)));     \
            fs1 = *(const float4*)(qf + ((unsigned)(pN).x * 64u + (unsigned)(p*8) + 4u));\
            fd0 = *(const float4*)(qf + ((unsigned)(pN).y * 64u + (unsigned)(p*8)));     \
            fd1 = *(const float4*)(qf + ((unsigned)(pN).y * 64u + (unsigned)(p*8) + 4u));\
        }                                                                         \
        ps0 = pos[(unsigned)(pN).x * 3u];  ps1 = pos[(unsigned)(pN).x * 3u + 1u]; \
        ps2 = pos[(unsigned)(pN).x * 3u + 2u];                                    \
        pd0 = pos[(unsigned)(pN).y * 3u];  pd1 = pos[(unsigned)(pN).y * 3u + 1u]; \
        pd2 = pos[(unsigned)(pN).y * 3u + 2u];

    #define STAGE(buf)                                                            \
        {                                                                         \
            bf16x8 cv;                                                            \
            if constexpr (USEBF) {                                                \
                _Pragma("unroll")                                                 \
                for (int j = 0; j < 8; ++j)                                       \
                    cv[j] = (__bf16)((float)gs[j] + (float)gd[j]);                \
            } else {                                                              \
                cv[0] = (__bf16)(fs0.x + fd0.x); cv[1] = (__bf16)(fs0.y + fd0.y); \
                cv[2] = (__bf16)(fs0.z + fd0.z); cv[3] = (__bf16)(fs0.w + fd0.w); \
                cv[4] = (__bf16)(fs1.x + fd1.x); cv[5] = (__bf16)(fs1.y + fd1.y); \
                cv[6] = (__bf16)(fs1.z + fd1.z); cv[7] = (__bf16)(fs1.w + fd1.w); \
            }                                                                     \
            *(bf16x8*)(&sm.comb[buf][e_loc][p * 8]) = cv;                         \
            const float dx = ps0 - pd0, dy = ps1 - pd1, dz = ps2 - pd2;           \
            const float D  = sqrtf(fmaxf(dx * dx + dy * dy + dz * dz, 1e-8f));    \
            bf16x4 rv;                                                            \
            _Pragma("unroll")                                                     \
            for (int j = 0; j < 4; ++j) {                                         \
                const float mu = (float)(p * 4 + j) * (10.0f / 31.0f);            \
                const float z  = (D - mu) * 3.2f;                                 \
                rv[j] = (__bf16)__expf(-z * z);                                   \
            }                                                                     \
            *(bf16x4*)(&sm.comb[buf][e_loc][64 + p * 4]) = rv;                    \
        }

    GATHER(pA);
    {
        const int tn = tile + ENBLK;
        pA = ((const int2*)pair)[(tn < ETILES ? (size_t)tn * ETILE : 0) + e_loc];
    }
    STAGE(0);
    GATHER(pA);
    {
        const int tn = tile + 2 * ENBLK;
        pA = ((const int2*)pair)[(tn < ETILES ? (size_t)tn * ETILE : 0) + e_loc];
    }
    bar_lgkm();

    int cur = 0;
    int e0_prev = -1;

    for (; tile < ETILES; tile += ENBLK) {
        const int e0 = tile * ETILE;

        // 1. epilogue for previous tile
        if (e0_prev >= 0 && t < 160) {
            const int m = t / 5, o = t % 5;
            const int mt = m >> 4, rr = m & 15;
            const int hh = rr >> 2, r = rr & 3;
            float s = bb2[o];
            #pragma unroll
            for (int ww = 0; ww < 4; ++ww)
                s += sm.red[cur ^ 1][ww][mt][r][hh * 16 + o];
            outC[(size_t)(e0_prev + m) * NBOND + o] = s;
        }

        // 2. stage comb[cur^1] from in-flight gathers
        STAGE(cur ^ 1);

        // 3. issue gathers for tile+2*ENBLK; pair for tile+3*ENBLK
        GATHER(pA);
        {
            const int tn = tile + 3 * ENBLK;
            pA = ((const int2*)pair)[(tn < ETILES ? (size_t)tn * ETILE : 0) + e_loc];
        }

        // 4. layer 1 on comb[cur]: wave = 64 hidden x 32 edges
        f32x4 acc[2][4];
        #pragma unroll
        for (int mt = 0; mt < 2; ++mt)
            #pragma unroll
            for (int nt = 0; nt < 4; ++nt)
                #pragma unroll
                for (int r = 0; r < 4; ++r)
                    acc[mt][nt][r] = ((const float*)&b1v[nt])[r];

        #pragma unroll
        for (int kb = 0; kb < 3; ++kb)
            #pragma unroll
            for (int mt = 0; mt < 2; ++mt) {
                const bf16x8 bf = *(const bf16x8*)((const char*)&sm.comb[cur][0][0]
                                   + (mt * 16 + l15) * 208 + kb * 64 + hi * 16);
                #pragma unroll
                for (int nt = 0; nt < 4; ++nt)
                    acc[mt][nt] = __builtin_amdgcn_mfma_f32_16x16x32_bf16(
                        bw1f[kb][nt], bf, acc[mt][nt], 0, 0, 0);
            }

        // 5. layer 2 fully in-register: relu+pack -> 16x16x16 MFMA chain
        {
            f32x4 acc2[2];
            {
                f32x4 z = {0.f, 0.f, 0.f, 0.f};
                acc2[0] = z; acc2[1] = z;
            }
            #pragma unroll
            for (int mt = 0; mt < 2; ++mt)
                #pragma unroll
                for (int nt = 0; nt < 4; ++nt) {
                    bf16x4 hv;
                    #pragma unroll
                    for (int r = 0; r < 4; ++r)
                        hv[r] = (__bf16)fmaxf(acc[mt][nt][r], 0.f);
                    acc2[mt] = mfma16(hv, w2f[nt], acc2[mt]);
                }
            #pragma unroll
            for (int mt = 0; mt < 2; ++mt)
                #pragma unroll
                for (int r = 0; r < 4; ++r)
                    sm.red[cur][w][mt][r][lane] = acc2[mt][r];
        }

        e0_prev = e0;
        bar_lgkm();     // comb[cur^1] + red[cur] visible
        cur ^= 1;
    }

    // final epilogue
    if (e0_prev >= 0 && t < 160) {
        const int m = t / 5, o = t % 5;
        const int mt = m >> 4, rr = m & 15;
        const int hh = rr >> 2, r = rr & 3;
        float s = bb2[o];
        #pragma unroll
        for (int ww = 0; ww < 4; ++ww)
            s += sm.red[cur ^ 1][ww][mt][r][hh * 16 + o];
        outC[(size_t)(e0_prev + m) * NBOND + o] = s;
    }
    #undef GATHER
    #undef STAGE
}

// ---------------------------------------------------------------------------
extern "C" void kernel_launch(void* const* d_in, const int* in_sizes, int n_in,
                              void* d_out, int out_size, void* d_ws, size_t ws_size,
                              hipStream_t stream)
{
    const float* pos = (const float*)d_in[0];
    const float* q   = (const float*)d_in[1];
    const int*   pair= (const int*)  d_in[2];
    const float* aW1 = (const float*)d_in[3];
    const float* ab1 = (const float*)d_in[4];
    const float* aW2 = (const float*)d_in[5];
    const float* ab2 = (const float*)d_in[6];
    const float* bW1 = (const float*)d_in[7];
    const float* bb1 = (const float*)d_in[8];
    const float* bW2 = (const float*)d_in[9];
    const float* bb2 = (const float*)d_in[10];

    float* out  = (float*)d_out;
    float* outA = out;
    float* outB = out + (size_t)N_NODES * NTYPES;
    float* outC = out + (size_t)N_NODES * (NTYPES + NCHG);

    const size_t qb_bytes = (size_t)N_NODES * LATENT * sizeof(__bf16);
    const bool use_bf = (ws_size >= qb_bytes);
    __bf16* qb = (__bf16*)d_ws;

    if (use_bf)
        hipLaunchKernelGGL(atom_kernel<true>, dim3(ANBLK), dim3(256), 0, stream,
                           q, aW1, ab1, aW2, ab2, outA, outB, qb);
    else
        hipLaunchKernelGGL(atom_kernel<false>, dim3(ANBLK), dim3(256), 0, stream,
                           q, aW1, ab1, aW2, ab2, outA, outB, qb);

    if (use_bf)
        hipLaunchKernelGGL(edge_kernel<true>, dim3(ENBLK), dim3(256), 0, stream,
                           pos, q, qb, pair, bW1, bb1, bW2, bb2, outC);
    else
        hipLaunchKernelGGL(edge_kernel<false>, dim3(ENBLK), dim3(256), 0, stream,
                           pos, q, qb, pair, bW1, bb1, bW2, bb2, outC);
}